// Round 8
// baseline (235.377 us; speedup 1.0000x reference)
//
#include <hip/hip_runtime.h>
#include <math.h>

#define R_N 4096
#define D_N 4096
#define C_N 20
#define IMG_W_F 1216.0f
#define IMG_H_F 800.0f
#define SCORE_TH 0.05f
#define NMS_TH 0.5f
#define TOPK_N 100

// ---- workspace layout (units: 4-byte words) ----
// Wfrag: 128 gs x 2 ct x 64 lanes x 16 B = 256 KB (det cols 0..20, 21..31 zero)
#define WF_WORDS   (128 * 2 * 64 * 4)                // 65536
#define EDET_OFF   (WF_WORDS)                        // edet[4096][24] f32 (cols 0..19 valid)
#define EDET_WORDS (R_N * 24)
#define CTRL_OFF   (EDET_OFF + EDET_WORDS)           // dsum f32[24] | nc i32[20] | done i32 -> 64 words
#define CAND_R_OFF (CTRL_OFF + 64)                   // 20*32 ints
#define CAND_D_OFF (CAND_R_OFF + 640)                // 20*32 f32 (det_sm)
#define CAND_S_OFF (CAND_D_OFF + 640)                // 20*32 f32 (final score)

typedef short bf16x8 __attribute__((ext_vector_type(8)));
typedef float f32x4  __attribute__((ext_vector_type(4)));

// truncating bf16 pack: {hi16(a), hi16(b)} -> lo short = bf16(b), hi short = bf16(a)
__device__ __forceinline__ unsigned pk(float a, float b) {
  return __builtin_amdgcn_perm(__float_as_uint(a), __float_as_uint(b), 0x07060302u);
}
__device__ __forceinline__ float fexp(float x) { return __expf(x); }

__device__ __forceinline__ void load_clip_box(const float* boxes, int r, float* b) {
  b[0] = fminf(fmaxf(boxes[r * 4 + 0], 0.f), IMG_W_F);
  b[1] = fminf(fmaxf(boxes[r * 4 + 1], 0.f), IMG_H_F);
  b[2] = fminf(fmaxf(boxes[r * 4 + 2], 0.f), IMG_W_F);
  b[3] = fminf(fmaxf(boxes[r * 4 + 3], 0.f), IMG_H_F);
}

// ============ pack W_det -> frag-linear bf16; zero control words ============
// entry e: l=e&63, ct=(e>>6)&1, gs=e>>7
// holds B[k = gs*32 + (l>>4)*8 + j][col = ct*16 + (l&15)], j=0..7
__global__ __launch_bounds__(256) void wT_kernel(
    const float* __restrict__ Wd, uint4* __restrict__ Wfrag,
    float* __restrict__ ctrl) {
  const int e = blockIdx.x * 256 + threadIdx.x;     // 64 blocks -> 16384
  const int l = e & 63;
  const int ct = (e >> 6) & 1;
  const int gs = e >> 7;
  const int c = ct * 16 + (l & 15);
  const int k0 = gs * 32 + (l >> 4) * 8;
  float w[8];
  if (c < 21) {
#pragma unroll
    for (int j = 0; j < 8; j++) w[j] = Wd[(size_t)(k0 + j) * 21 + c];
  } else {
#pragma unroll
    for (int j = 0; j < 8; j++) w[j] = 0.f;
  }
  uint4 v;
  v.x = pk(w[1], w[0]); v.y = pk(w[3], w[2]);
  v.z = pk(w[5], w[4]); v.w = pk(w[7], w[6]);
  Wfrag[(gs * 2 + ct) * 64 + l] = v;
  if (e < 64) ctrl[e] = 0.f;                        // dsum + nc + done
}

// ============ det GEMM + fused tail (last-block-done) ============
// 256 blocks x 1024 thr (16 waves). Block = 16 rows; wave w: K [w*256,(w+1)*256).
// Barrier-free K-loop; A direct from global (trunc->bf16), B from L2 (frag-linear).
// Epilogue: 16-way LDS K-reduce -> edet=exp(detlog) + dsum atomics.
// Block #255 (done-counter) then: candidate scan -> cls-on-demand -> NMS -> top-100.
__global__ __launch_bounds__(1024) void detgemm_kernel(
    const float* __restrict__ x, const uint4* __restrict__ Wfrag,
    const float* __restrict__ Wc, const float* __restrict__ b_cls,
    const float* __restrict__ boxes,
    float* __restrict__ edet, float* __restrict__ dsum,
    int* __restrict__ nc, int* __restrict__ done,
    int* __restrict__ cand_r, float* __restrict__ cand_d, float* __restrict__ cand_s,
    float* __restrict__ out) {
  __shared__ char smem[32768];                      // red[16][512] f32; tail overlays
  __shared__ bool s_last;
  float* red = (float*)smem;
  const int t = threadIdx.x;
  const int w = t >> 6, l = t & 63;
  const int r16 = l & 15, q = l >> 4;
  const int r0 = blockIdx.x * 16;

  // ---- K-loop ----
  const float* xrow = x + (size_t)(r0 + r16) * D_N + w * 256 + q * 8;
  f32x4 acc0 = {0.f, 0.f, 0.f, 0.f};
  f32x4 acc1 = {0.f, 0.f, 0.f, 0.f};
#pragma unroll
  for (int s = 0; s < 8; s++) {
    float4 a0 = *(const float4*)(xrow + s * 32);
    float4 a1 = *(const float4*)(xrow + s * 32 + 4);
    const int gs = w * 8 + s;
    union { uint4 u; bf16x8 v; } b0, b1;
    b0.u = Wfrag[(gs * 2 + 0) * 64 + l];
    b1.u = Wfrag[(gs * 2 + 1) * 64 + l];
    union { bf16x8 v; unsigned u[4]; } af;
    af.u[0] = pk(a0.y, a0.x);
    af.u[1] = pk(a0.w, a0.z);
    af.u[2] = pk(a1.y, a1.x);
    af.u[3] = pk(a1.w, a1.z);
    acc0 = __builtin_amdgcn_mfma_f32_16x16x32_bf16(af.v, b0.v, acc0, 0, 0, 0);
    acc1 = __builtin_amdgcn_mfma_f32_16x16x32_bf16(af.v, b1.v, acc1, 0, 0, 0);
  }

  // ---- cross-wave K-reduction: lane l, reg j = D[row=q*4+j][col=ct*16+r16] ----
  *(f32x4*)(&red[w * 512 + (0  + r16) * 16 + q * 4]) = acc0;
  *(f32x4*)(&red[w * 512 + (16 + r16) * 16 + q * 4]) = acc1;
  __syncthreads();
  if (t < 512) {                                    // o = c*16 + r
    float v = 0.f;
#pragma unroll
    for (int w2 = 0; w2 < 16; w2++) v += red[w2 * 512 + t];
    red[t] = v;
  }
  __syncthreads();
  if (t < 20) {                                     // det class c = t (background col unused)
    float s = 0.f;
#pragma unroll
    for (int r = 0; r < 16; r++) {
      float e = fexp(red[t * 16 + r]);
      edet[(size_t)(r0 + r) * 24 + t] = e;
      s += e;
    }
    atomicAdd(&dsum[t], s);
  }
  __threadfence();
  __syncthreads();
  if (t == 0) s_last = (atomicAdd(done, 1) == 255);
  __syncthreads();
  if (!s_last) return;
  __threadfence();                                  // acquire: edet/dsum from all blocks

  // ======== tail (one block, 1024 threads) ========
  float* sd   = (float*)smem;                       // 20 f32
  int*   s_kc = (int*)(smem + 128);
  int*   s_ki = (int*)(smem + 256);                 // 512 i32
  float* s_ks = (float*)(smem + 2304);              // 512 f32
  float* sval = (float*)(smem + 4352);              // 100 f32
  int*   sidx = (int*)(smem + 4864);                // 100 i32
  if (t < 20) sd[t] = dsum[t];
  if (t == 0) *s_kc = 0;
  if (t < TOPK_N) { sval[t] = 0.f; sidx[t] = 0; }
  __syncthreads();

  // ---- candidate scan: det_sm > TH is a superset of score > TH (<=20/class) ----
#pragma unroll
  for (int j = 0; j < 4; j++) {
    const int r = t + j * 1024;
    for (int c = 0; c < 20; c++) {
      float dsm = edet[(size_t)r * 24 + c] / sd[c];
      if (dsm > SCORE_TH) {
        int p = atomicAdd(&nc[c], 1);
        if (p < 32) { cand_r[c * 32 + p] = r; cand_d[c * 32 + p] = dsm; }
      }
    }
  }
  __syncthreads();

  // ---- exact scores for candidates: cls logits on demand ----
  for (int slot = t; slot < 640; slot += 1024) {
    const int c = slot >> 5, i = slot & 31;
    int n = nc[c]; if (n > 32) n = 32;
    if (i < n) {
      const int rr = cand_r[slot];
      float lg[21];
#pragma unroll
      for (int j = 0; j < 21; j++) lg[j] = b_cls[j];
      const float* xr = x + (size_t)rr * D_N;
      for (int k = 0; k < D_N; k++) {
        float xv = xr[k];
        const float* wr = Wc + (size_t)k * 21;
#pragma unroll
        for (int j = 0; j < 21; j++) lg[j] = fmaf(xv, wr[j], lg[j]);
      }
      float m = -1e30f;
#pragma unroll
      for (int j = 0; j < 21; j++) m = fmaxf(m, lg[j]);
      float s = 0.f;
#pragma unroll
      for (int j = 0; j < 21; j++) s += fexp(lg[j] - m);
      float p = fexp(lg[c] - m) / s;
      cand_s[slot] = p * cand_d[slot];
    }
  }
  __syncthreads();

  // ---- per-class greedy NMS on score>TH candidates ----
  if (t < 20) {
    const int c = t;
    int n = nc[c]; if (n > 32) n = 32;
    float s[32]; int rr[32]; int n2 = 0;
    for (int i = 0; i < n; i++) {
      float sc = cand_s[c * 32 + i];
      if (sc > SCORE_TH) { s[n2] = sc; rr[n2] = cand_r[c * 32 + i]; n2++; }
    }
    for (int i = 1; i < n2; i++) {                  // score desc, tie -> row asc
      float si = s[i]; int ri = rr[i];
      int j = i - 1;
      while (j >= 0 && (s[j] < si || (s[j] == si && rr[j] > ri))) {
        s[j + 1] = s[j]; rr[j + 1] = rr[j]; j--;
      }
      s[j + 1] = si; rr[j + 1] = ri;
    }
    unsigned supp = 0;
    for (int i = 0; i < n2; i++) {
      if (supp & (1u << i)) continue;
      int g = atomicAdd(s_kc, 1);
      if (g < 512) { s_ki[g] = rr[i] * C_N + c; s_ks[g] = s[i]; }
      float bi[4]; load_clip_box(boxes, rr[i], bi);
      float ai = (bi[2] - bi[0]) * (bi[3] - bi[1]);
      for (int j = i + 1; j < n2; j++) {
        if (supp & (1u << j)) continue;
        float bj[4]; load_clip_box(boxes, rr[j], bj);
        float aj = (bj[2] - bj[0]) * (bj[3] - bj[1]);
        float lx = fmaxf(bi[0], bj[0]), ly = fmaxf(bi[1], bj[1]);
        float rx = fminf(bi[2], bj[2]), ry = fminf(bi[3], bj[3]);
        float wdt = fmaxf(rx - lx, 0.f), hgt = fmaxf(ry - ly, 0.f);
        float inter = wdt * hgt;
        float iou = inter / (ai + aj - inter + 1e-9f);
        if (iou > NMS_TH) supp |= (1u << j);
      }
    }
  }
  __syncthreads();

  // ---- top-100 with jax.lax.top_k tie rules ----
  int m = *s_kc; if (m > 512) m = 512;
  for (int i = t; i < m; i += 1024) {
    float si = s_ks[i]; int xi = s_ki[i];
    int rank = 0;
    for (int j = 0; j < m; j++) {
      float sj = s_ks[j]; int xj = s_ki[j];
      if (sj > si || (sj == si && xj < xi)) rank++;
    }
    if (rank < TOPK_N) { sval[rank] = si; sidx[rank] = xi; }
  }
  __syncthreads();
  if (t == 0) {
    int f = m < TOPK_N ? m : TOPK_N;
    int cur = 0;
    for (int slot = f; slot < TOPK_N; slot++) {
      for (;;) {
        bool member = false;
        for (int j = 0; j < m; j++)
          if (s_ki[j] == cur) { member = true; break; }
        if (!member) break;
        cur++;
      }
      sval[slot] = 0.f;
      sidx[slot] = cur;
      cur++;
    }
  }
  __syncthreads();
  if (t < TOPK_N) {
    int idx = sidx[t];
    int prop = idx / C_N;
    int cls = idx - prop * C_N;
    float b[4]; load_clip_box(boxes, prop, b);
    out[t] = sval[t];
    out[TOPK_N + t * 4 + 0] = b[0];
    out[TOPK_N + t * 4 + 1] = b[1];
    out[TOPK_N + t * 4 + 2] = b[2];
    out[TOPK_N + t * 4 + 3] = b[3];
    out[TOPK_N * 5 + t] = (float)cls;
  }
}

extern "C" void kernel_launch(void* const* d_in, const int* in_sizes, int n_in,
                              void* d_out, int out_size, void* d_ws, size_t ws_size,
                              hipStream_t stream) {
  const float* x     = (const float*)d_in[0];
  const float* boxes = (const float*)d_in[1];
  const float* W_cls = (const float*)d_in[2];
  const float* b_cls = (const float*)d_in[3];
  const float* W_det = (const float*)d_in[4];
  // b_det unused: column-softmax bias cancels

  float* out = (float*)d_out;
  float* ws = (float*)d_ws;
  uint4* Wfrag    = (uint4*)ws;
  float* edet     = ws + EDET_OFF;
  float* dsum     = ws + CTRL_OFF;                  // 24 f32
  int*   nc       = (int*)(ws + CTRL_OFF) + 24;     // 20 i32
  int*   done     = (int*)(ws + CTRL_OFF) + 44;     // 1 i32
  int*   cand_r   = (int*)(ws + CAND_R_OFF);
  float* cand_d   = ws + CAND_D_OFF;
  float* cand_s   = ws + CAND_S_OFF;

  wT_kernel     <<<64,  256,  0, stream>>>(W_det, Wfrag, dsum);
  detgemm_kernel<<<256, 1024, 0, stream>>>(x, Wfrag, W_cls, b_cls, boxes,
                                           edet, dsum, nc, done,
                                           cand_r, cand_d, cand_s, out);
}

// Round 9
// 123.065 us; speedup vs baseline: 1.9126x; 1.9126x over previous
//
#include <hip/hip_runtime.h>
#include <math.h>

#define R_N 4096
#define D_N 4096
#define C_N 20
#define IMG_W_F 1216.0f
#define IMG_H_F 800.0f
#define SCORE_TH 0.05f
#define NMS_TH 0.5f
#define TOPK_N 100

// ---- workspace layout (units: 4-byte words) ----
// Wfrag: 128 gs x 2 ct x 64 lanes x 16 B = 256 KB (det cols 0..20, 21..31 zero)
#define WF_WORDS   (128 * 2 * 64 * 4)                // 65536
#define DET_OFF    (WF_WORDS)                        // detlog[4096][24] f32 (cols 0..20 valid)
#define DET_WORDS  (R_N * 24)
#define CTRL_OFF   (DET_OFF + DET_WORDS)             // dsum f32[24] | nc i32[20] | done i32 -> 64 words
#define CAND_R_OFF (CTRL_OFF + 64)                   // 20*32 ints
#define CAND_D_OFF (CAND_R_OFF + 640)                // 20*32 f32 (det_sm)
#define CAND_S_OFF (CAND_D_OFF + 640)                // 20*32 f32 (final score)

typedef short bf16x8 __attribute__((ext_vector_type(8)));
typedef float f32x4  __attribute__((ext_vector_type(4)));

// truncating bf16 pack: {hi16(a), hi16(b)} -> lo short = bf16(b), hi short = bf16(a)
__device__ __forceinline__ unsigned pk(float a, float b) {
  return __builtin_amdgcn_perm(__float_as_uint(a), __float_as_uint(b), 0x07060302u);
}
__device__ __forceinline__ float fexp(float x) { return __expf(x); }

// ============ pack W_det -> frag-linear bf16; zero control words ============
// entry e: l=e&63, ct=(e>>6)&1, gs=e>>7
// holds B[k = gs*32 + (l>>4)*8 + j][col = ct*16 + (l&15)], j=0..7
__global__ __launch_bounds__(256) void wT_kernel(
    const float* __restrict__ Wd, uint4* __restrict__ Wfrag,
    float* __restrict__ ctrl) {
  const int e = blockIdx.x * 256 + threadIdx.x;     // 64 blocks -> 16384
  const int l = e & 63;
  const int ct = (e >> 6) & 1;
  const int gs = e >> 7;
  const int c = ct * 16 + (l & 15);
  const int k0 = gs * 32 + (l >> 4) * 8;
  float w[8];
  if (c < 21) {
#pragma unroll
    for (int j = 0; j < 8; j++) w[j] = Wd[(size_t)(k0 + j) * 21 + c];
  } else {
#pragma unroll
    for (int j = 0; j < 8; j++) w[j] = 0.f;
  }
  uint4 v;
  v.x = pk(w[1], w[0]); v.y = pk(w[3], w[2]);
  v.z = pk(w[5], w[4]); v.w = pk(w[7], w[6]);
  Wfrag[(gs * 2 + ct) * 64 + l] = v;
  if (e < 64) ctrl[e] = 0.f;                        // dsum + nc + done
}

// ============ det GEMM: detlog[r][c] = x[r,:] @ Wd[:,c], full K in one block ============
// 256 blocks x 1024 thr (16 waves). Block = 16 rows; wave w: K [w*256,(w+1)*256).
// A: ALL 16 float4 loads issued up-front (64 VGPRs) -> max memory-level parallelism.
// B: from L2 (frag-linear, 256 KB). No barriers in the K-loop.
// Epilogue: in-block 16-way LDS reduce -> detlog + per-class exp-sum atomics (bias cancels).
__global__ __launch_bounds__(1024) void detgemm_kernel(
    const float* __restrict__ x, const uint4* __restrict__ Wfrag,
    float* __restrict__ detlog, float* __restrict__ dsum) {
  __shared__ float red[16 * 512];                   // 32 KB
  const int t = threadIdx.x;
  const int w = t >> 6, l = t & 63;
  const int r16 = l & 15, q = l >> 4;
  const int r0 = blockIdx.x * 16;

  const float* xrow = x + (size_t)(r0 + r16) * D_N + w * 256 + q * 8;

  // ---- prefetch all A (16 rows x 256 K for this wave): 16 outstanding HBM loads ----
  float4 a[16];
#pragma unroll
  for (int s = 0; s < 8; s++) {
    a[2 * s]     = *(const float4*)(xrow + s * 32);
    a[2 * s + 1] = *(const float4*)(xrow + s * 32 + 4);
  }

  f32x4 acc0 = {0.f, 0.f, 0.f, 0.f};
  f32x4 acc1 = {0.f, 0.f, 0.f, 0.f};
#pragma unroll
  for (int s = 0; s < 8; s++) {
    const int gs = w * 8 + s;
    union { uint4 u; bf16x8 v; } b0, b1;
    b0.u = Wfrag[(gs * 2 + 0) * 64 + l];
    b1.u = Wfrag[(gs * 2 + 1) * 64 + l];
    union { bf16x8 v; unsigned u[4]; } af;
    af.u[0] = pk(a[2 * s].y,     a[2 * s].x);
    af.u[1] = pk(a[2 * s].w,     a[2 * s].z);
    af.u[2] = pk(a[2 * s + 1].y, a[2 * s + 1].x);
    af.u[3] = pk(a[2 * s + 1].w, a[2 * s + 1].z);
    acc0 = __builtin_amdgcn_mfma_f32_16x16x32_bf16(af.v, b0.v, acc0, 0, 0, 0);
    acc1 = __builtin_amdgcn_mfma_f32_16x16x32_bf16(af.v, b1.v, acc1, 0, 0, 0);
  }

  // lane l, reg j holds D[row = q*4+j][col = ct*16 + r16]; red layout [w][c][r]
  *(f32x4*)(&red[w * 512 + (0  + r16) * 16 + q * 4]) = acc0;
  *(f32x4*)(&red[w * 512 + (16 + r16) * 16 + q * 4]) = acc1;
  __syncthreads();
  if (t < 512) {                                    // o = c*16 + r
    float v = 0.f;
#pragma unroll
    for (int w2 = 0; w2 < 16; w2++) v += red[w2 * 512 + t];
    red[t] = v;                                     // each loc read only by its own thread
  }
  __syncthreads();
  if (t < 21) {                                     // class c = t
    float s = 0.f;
#pragma unroll
    for (int r = 0; r < 16; r++) {
      float v = red[t * 16 + r];
      detlog[(size_t)(r0 + r) * 24 + t] = v;
      s += fexp(v);
    }
    atomicAdd(&dsum[t], s);
  }
}

// ============ finish: det-candidates; last block: cls-on-demand -> NMS -> top-100 ============
__device__ __forceinline__ void load_clip_box(const float* boxes, int r, float* b) {
  b[0] = fminf(fmaxf(boxes[r * 4 + 0], 0.f), IMG_W_F);
  b[1] = fminf(fmaxf(boxes[r * 4 + 1], 0.f), IMG_H_F);
  b[2] = fminf(fmaxf(boxes[r * 4 + 2], 0.f), IMG_W_F);
  b[3] = fminf(fmaxf(boxes[r * 4 + 3], 0.f), IMG_H_F);
}

__global__ __launch_bounds__(256) void finish_kernel(
    const float* __restrict__ x, const float* __restrict__ Wc,
    const float* __restrict__ b_cls, const float* __restrict__ detlog,
    const float* __restrict__ dsum, int* __restrict__ nc, int* __restrict__ done,
    int* __restrict__ cand_r, float* __restrict__ cand_d, float* __restrict__ cand_s,
    const float* __restrict__ boxes, float* __restrict__ out) {
  __shared__ float sd[20];
  __shared__ bool s_last;
  const int t = threadIdx.x;
  if (t < 20) sd[t] = dsum[t];
  __syncthreads();

  // ---- phase 1 (all 16 blocks): det-softmax candidate detection ----
  // score <= det_sm, so {det_sm > TH} is a superset of {score > TH}; <=20 rows/class.
  const int r = blockIdx.x * 256 + t;
  for (int c = 0; c < 20; c++) {
    float dsm = fexp(detlog[(size_t)r * 24 + c]) / sd[c];
    if (dsm > SCORE_TH) {
      int p = atomicAdd(&nc[c], 1);
      if (p < 32) { cand_r[c * 32 + p] = r; cand_d[c * 32 + p] = dsm; }
    }
  }
  __threadfence();
  __syncthreads();
  if (t == 0) s_last = (atomicAdd(done, 1) == 15);
  __syncthreads();
  if (!s_last) return;
  __threadfence();

  // ---- phase 2 (last block): exact scores for candidates (cls logits on demand) ----
  for (int slot = t; slot < 640; slot += 256) {
    const int c = slot >> 5, i = slot & 31;
    int n = nc[c]; if (n > 32) n = 32;
    if (i < n) {
      const int rr = cand_r[slot];
      float lg[21];
#pragma unroll
      for (int j = 0; j < 21; j++) lg[j] = b_cls[j];
      const float* xr = x + (size_t)rr * D_N;
      for (int k = 0; k < D_N; k++) {
        float xv = xr[k];
        const float* wr = Wc + (size_t)k * 21;
#pragma unroll
        for (int j = 0; j < 21; j++) lg[j] = fmaf(xv, wr[j], lg[j]);
      }
      float m = -1e30f;
#pragma unroll
      for (int j = 0; j < 21; j++) m = fmaxf(m, lg[j]);
      float s = 0.f;
#pragma unroll
      for (int j = 0; j < 21; j++) s += fexp(lg[j] - m);
      float p = fexp(lg[c] - m) / s;
      cand_s[slot] = p * cand_d[slot];
    }
  }
  __syncthreads();

  // ---- per-class NMS on score>TH candidates ----
  __shared__ int   s_kc;
  __shared__ int   s_ki[512];
  __shared__ float s_ks[512];
  __shared__ float sval[TOPK_N];
  __shared__ int   sidx[TOPK_N];
  if (t == 0) s_kc = 0;
  if (t < TOPK_N) { sval[t] = 0.f; sidx[t] = 0; }
  __syncthreads();

  if (t < 20) {
    const int c = t;
    int n = nc[c]; if (n > 32) n = 32;
    float s[32]; int rr[32]; int n2 = 0;
    for (int i = 0; i < n; i++) {
      float sc = cand_s[c * 32 + i];
      if (sc > SCORE_TH) { s[n2] = sc; rr[n2] = cand_r[c * 32 + i]; n2++; }
    }
    for (int i = 1; i < n2; i++) {                  // score desc, tie -> row asc
      float si = s[i]; int ri = rr[i];
      int j = i - 1;
      while (j >= 0 && (s[j] < si || (s[j] == si && rr[j] > ri))) {
        s[j + 1] = s[j]; rr[j + 1] = rr[j]; j--;
      }
      s[j + 1] = si; rr[j + 1] = ri;
    }
    unsigned supp = 0;
    for (int i = 0; i < n2; i++) {
      if (supp & (1u << i)) continue;
      int g = atomicAdd(&s_kc, 1);
      if (g < 512) { s_ki[g] = rr[i] * C_N + c; s_ks[g] = s[i]; }
      float bi[4]; load_clip_box(boxes, rr[i], bi);
      float ai = (bi[2] - bi[0]) * (bi[3] - bi[1]);
      for (int j = i + 1; j < n2; j++) {
        if (supp & (1u << j)) continue;
        float bj[4]; load_clip_box(boxes, rr[j], bj);
        float aj = (bj[2] - bj[0]) * (bj[3] - bj[1]);
        float lx = fmaxf(bi[0], bj[0]), ly = fmaxf(bi[1], bj[1]);
        float rx = fminf(bi[2], bj[2]), ry = fminf(bi[3], bj[3]);
        float wdt = fmaxf(rx - lx, 0.f), hgt = fmaxf(ry - ly, 0.f);
        float inter = wdt * hgt;
        float iou = inter / (ai + aj - inter + 1e-9f);
        if (iou > NMS_TH) supp |= (1u << j);
      }
    }
  }
  __syncthreads();

  // ---- top-100 with jax.lax.top_k tie rules ----
  int m = s_kc; if (m > 512) m = 512;
  for (int i = t; i < m; i += 256) {
    float si = s_ks[i]; int xi = s_ki[i];
    int rank = 0;
    for (int j = 0; j < m; j++) {
      float sj = s_ks[j]; int xj = s_ki[j];
      if (sj > si || (sj == si && xj < xi)) rank++;
    }
    if (rank < TOPK_N) { sval[rank] = si; sidx[rank] = xi; }
  }
  __syncthreads();
  if (t == 0) {
    int f = m < TOPK_N ? m : TOPK_N;
    int cur = 0;
    for (int slot = f; slot < TOPK_N; slot++) {
      for (;;) {
        bool member = false;
        for (int j = 0; j < m; j++)
          if (s_ki[j] == cur) { member = true; break; }
        if (!member) break;
        cur++;
      }
      sval[slot] = 0.f;
      sidx[slot] = cur;
      cur++;
    }
  }
  __syncthreads();
  if (t < TOPK_N) {
    int idx = sidx[t];
    int prop = idx / C_N;
    int cls = idx - prop * C_N;
    float b[4]; load_clip_box(boxes, prop, b);
    out[t] = sval[t];
    out[TOPK_N + t * 4 + 0] = b[0];
    out[TOPK_N + t * 4 + 1] = b[1];
    out[TOPK_N + t * 4 + 2] = b[2];
    out[TOPK_N + t * 4 + 3] = b[3];
    out[TOPK_N * 5 + t] = (float)cls;
  }
}

extern "C" void kernel_launch(void* const* d_in, const int* in_sizes, int n_in,
                              void* d_out, int out_size, void* d_ws, size_t ws_size,
                              hipStream_t stream) {
  const float* x     = (const float*)d_in[0];
  const float* boxes = (const float*)d_in[1];
  const float* W_cls = (const float*)d_in[2];
  const float* b_cls = (const float*)d_in[3];
  const float* W_det = (const float*)d_in[4];
  // b_det unused: column-softmax bias cancels

  float* out = (float*)d_out;
  float* ws = (float*)d_ws;
  uint4* Wfrag    = (uint4*)ws;
  float* detlog   = ws + DET_OFF;
  float* dsum     = ws + CTRL_OFF;                  // 24 f32
  int*   nc       = (int*)(ws + CTRL_OFF) + 24;     // 20 i32
  int*   done     = (int*)(ws + CTRL_OFF) + 44;     // 1 i32
  int*   cand_r   = (int*)(ws + CAND_R_OFF);
  float* cand_d   = ws + CAND_D_OFF;
  float* cand_s   = ws + CAND_S_OFF;

  wT_kernel     <<<64,  256,  0, stream>>>(W_det, Wfrag, dsum);
  detgemm_kernel<<<256, 1024, 0, stream>>>(x, Wfrag, detlog, dsum);
  finish_kernel <<<16,  256,  0, stream>>>(x, W_cls, b_cls, detlog, dsum,
                                           nc, done, cand_r, cand_d, cand_s,
                                           boxes, out);
}